// Round 4
// baseline (41.937 us; speedup 1.0000x reference)
//
#include <hip/hip_runtime.h>
#include <math.h>

#define NJ 24
#define NV 6890
#define NB 128

// Ancestor chains (closest ancestor first), -1 padded. Max depth 8.
__constant__ int d_anc[NJ][8] = {
  {-1,-1,-1,-1,-1,-1,-1,-1},
  { 0,-1,-1,-1,-1,-1,-1,-1},
  { 0,-1,-1,-1,-1,-1,-1,-1},
  { 0,-1,-1,-1,-1,-1,-1,-1},
  { 1, 0,-1,-1,-1,-1,-1,-1},
  { 2, 0,-1,-1,-1,-1,-1,-1},
  { 3, 0,-1,-1,-1,-1,-1,-1},
  { 4, 1, 0,-1,-1,-1,-1,-1},
  { 5, 2, 0,-1,-1,-1,-1,-1},
  { 6, 3, 0,-1,-1,-1,-1,-1},
  { 7, 4, 1, 0,-1,-1,-1,-1},
  { 8, 5, 2, 0,-1,-1,-1,-1},
  { 9, 6, 3, 0,-1,-1,-1,-1},
  { 9, 6, 3, 0,-1,-1,-1,-1},
  { 9, 6, 3, 0,-1,-1,-1,-1},
  {12, 9, 6, 3, 0,-1,-1,-1},
  {13, 9, 6, 3, 0,-1,-1,-1},
  {14, 9, 6, 3, 0,-1,-1,-1},
  {16,13, 9, 6, 3, 0,-1,-1},
  {17,14, 9, 6, 3, 0,-1,-1},
  {18,16,13, 9, 6, 3, 0,-1},
  {19,17,14, 9, 6, 3, 0,-1},
  {20,18,16,13, 9, 6, 3, 0},
  {21,19,17,14, 9, 6, 3, 0}
};
__constant__ int d_par[NJ] = {-1,0,0,0,1,2,3,4,5,6,7,8,9,9,9,12,13,14,16,17,18,19,20,21};

// Kernel 1: per-batch Rodrigues + parallel ancestor-path chain + J-correction.
// Each of 24 threads composes its own global transform (depth <= 8), so no
// serial 24-step section. Writes Gc[b][m][12] (3x4 row-major) to ws.
__global__ __launch_bounds__(64) void chain_kernel(const float* __restrict__ J,
                                                   const float* __restrict__ pose,
                                                   float* __restrict__ Gc) {
    int b = blockIdx.x;
    int tid = threadIdx.x;
    __shared__ float A[NJ][12];   // local [R|t] per joint

    if (tid < NJ) {
        int i = tid;
        const float* p = pose + ((size_t)b * NJ + i) * 3;
        float rx = p[0], ry = p[1], rz = p[2];
        float ex = rx + 1e-8f, ey = ry + 1e-8f, ez = rz + 1e-8f;
        float theta = sqrtf(ex * ex + ey * ey + ez * ez);
        float inv = 1.0f / theta;
        float hx = rx * inv, hy = ry * inv, hz = rz * inv;
        float c = cosf(theta * (float)M_PI);
        float s = sinf(theta);
        float oc = 1.0f - c;
        const float* jp = J + ((size_t)b * NJ + i) * 3;
        int par = d_par[i];
        float tx, ty, tz;
        if (par < 0) {
            tx = jp[0]; ty = jp[1]; tz = jp[2];
        } else {
            const float* jq = J + ((size_t)b * NJ + par) * 3;
            tx = jp[0] - jq[0]; ty = jp[1] - jq[1]; tz = jp[2] - jq[2];
        }
        A[i][0]  = c + oc * hx * hx;
        A[i][1]  = oc * hx * hy - s * hz;
        A[i][2]  = oc * hx * hz + s * hy;
        A[i][3]  = tx;
        A[i][4]  = oc * hy * hx + s * hz;
        A[i][5]  = c + oc * hy * hy;
        A[i][6]  = oc * hy * hz - s * hx;
        A[i][7]  = ty;
        A[i][8]  = oc * hz * hx - s * hy;
        A[i][9]  = oc * hz * hy + s * hx;
        A[i][10] = c + oc * hz * hz;
        A[i][11] = tz;
    }
    __syncthreads();

    if (tid < NJ) {
        int i = tid;
        float M[12];
        #pragma unroll
        for (int j = 0; j < 12; j++) M[j] = A[i][j];

        for (int k = 0; k < 8; k++) {
            int p = d_anc[i][k];
            if (p < 0) break;
            float P[12];
            #pragma unroll
            for (int j = 0; j < 12; j++) P[j] = A[p][j];
            float N[12];
            #pragma unroll
            for (int r = 0; r < 3; r++) {
                float p0 = P[r*4+0], p1 = P[r*4+1], p2 = P[r*4+2], p3 = P[r*4+3];
                N[r*4+0] = p0 * M[0] + p1 * M[4] + p2 * M[8];
                N[r*4+1] = p0 * M[1] + p1 * M[5] + p2 * M[9];
                N[r*4+2] = p0 * M[2] + p1 * M[6] + p2 * M[10];
                N[r*4+3] = p0 * M[3] + p1 * M[7] + p2 * M[11] + p3;
            }
            #pragma unroll
            for (int j = 0; j < 12; j++) M[j] = N[j];
        }

        const float* jp = J + ((size_t)b * NJ + i) * 3;
        float jx = jp[0], jy = jp[1], jz = jp[2];
        float* o = Gc + ((size_t)b * NJ + i) * 12;
        #pragma unroll
        for (int r = 0; r < 3; r++) {
            float g0 = M[r*4+0], g1 = M[r*4+1], g2 = M[r*4+2], g3 = M[r*4+3];
            float corr = g0 * jx + g1 * jy + g2 * jz;
            o[r*4+0] = g0;
            o[r*4+1] = g1;
            o[r*4+2] = g2;
            o[r*4+3] = g3 - corr;
        }
    }
}

// Kernel 2: per-vertex skinning, 2 vertices/thread, Gc staged in LDS and read
// as broadcast ds_read_b128 (all lanes same address -> conflict-free).
// W loads chunked (one float4 per 4 joints per vertex) to keep VGPRs low.
__global__ __launch_bounds__(256) void lbs_kernel(const float* __restrict__ V,
                                                  const float* __restrict__ W,
                                                  const float* __restrict__ Gc,
                                                  float* __restrict__ out) {
    const int b = blockIdx.y;
    const int tid = threadIdx.x;
    const int n0 = blockIdx.x * 512 + tid;

    __shared__ float4 g4[NJ * 3];   // 72 float4 = Gc[b]
    if (tid < NJ * 3)
        g4[tid] = ((const float4*)(Gc + (size_t)b * NJ * 12))[tid];
    __syncthreads();

    if (n0 >= NV) return;
    const int n1 = n0 + 256;
    const bool has1 = (n1 < NV);
    const int n1c = has1 ? n1 : n0;   // safe address; result discarded if !has1

    const float4* __restrict__ wp0 = (const float4*)(W + ((size_t)b * NV + n0) * 24);
    const float4* __restrict__ wp1 = (const float4*)(W + ((size_t)b * NV + n1c) * 24);

    float4 Ta0 = {0,0,0,0}, Ta1 = {0,0,0,0}, Ta2 = {0,0,0,0};
    float4 Tb0 = {0,0,0,0}, Tb1 = {0,0,0,0}, Tb2 = {0,0,0,0};

    #pragma unroll
    for (int c = 0; c < 6; c++) {
        float4 wa4 = wp0[c];
        float4 wb4 = wp1[c];
        const float ua[4] = {wa4.x, wa4.y, wa4.z, wa4.w};
        const float ub[4] = {wb4.x, wb4.y, wb4.z, wb4.w};
        #pragma unroll
        for (int q = 0; q < 4; q++) {
            const int m = c * 4 + q;
            float4 g0 = g4[m * 3 + 0];
            float4 g1 = g4[m * 3 + 1];
            float4 g2 = g4[m * 3 + 2];
            float a = ua[q], bw = ub[q];
            Ta0.x = fmaf(a, g0.x, Ta0.x); Ta0.y = fmaf(a, g0.y, Ta0.y);
            Ta0.z = fmaf(a, g0.z, Ta0.z); Ta0.w = fmaf(a, g0.w, Ta0.w);
            Ta1.x = fmaf(a, g1.x, Ta1.x); Ta1.y = fmaf(a, g1.y, Ta1.y);
            Ta1.z = fmaf(a, g1.z, Ta1.z); Ta1.w = fmaf(a, g1.w, Ta1.w);
            Ta2.x = fmaf(a, g2.x, Ta2.x); Ta2.y = fmaf(a, g2.y, Ta2.y);
            Ta2.z = fmaf(a, g2.z, Ta2.z); Ta2.w = fmaf(a, g2.w, Ta2.w);
            Tb0.x = fmaf(bw, g0.x, Tb0.x); Tb0.y = fmaf(bw, g0.y, Tb0.y);
            Tb0.z = fmaf(bw, g0.z, Tb0.z); Tb0.w = fmaf(bw, g0.w, Tb0.w);
            Tb1.x = fmaf(bw, g1.x, Tb1.x); Tb1.y = fmaf(bw, g1.y, Tb1.y);
            Tb1.z = fmaf(bw, g1.z, Tb1.z); Tb1.w = fmaf(bw, g1.w, Tb1.w);
            Tb2.x = fmaf(bw, g2.x, Tb2.x); Tb2.y = fmaf(bw, g2.y, Tb2.y);
            Tb2.z = fmaf(bw, g2.z, Tb2.z); Tb2.w = fmaf(bw, g2.w, Tb2.w);
        }
    }

    {
        const float* vp = V + ((size_t)b * NV + n0) * 3;
        float vx = vp[0], vy = vp[1], vz = vp[2];
        float* op = out + ((size_t)b * NV + n0) * 3;
        op[0] = Ta0.x * vx + Ta0.y * vy + Ta0.z * vz + Ta0.w;
        op[1] = Ta1.x * vx + Ta1.y * vy + Ta1.z * vz + Ta1.w;
        op[2] = Ta2.x * vx + Ta2.y * vy + Ta2.z * vz + Ta2.w;
    }
    if (has1) {
        const float* vp = V + ((size_t)b * NV + n1) * 3;
        float vx = vp[0], vy = vp[1], vz = vp[2];
        float* op = out + ((size_t)b * NV + n1) * 3;
        op[0] = Tb0.x * vx + Tb0.y * vy + Tb0.z * vz + Tb0.w;
        op[1] = Tb1.x * vx + Tb1.y * vy + Tb1.z * vz + Tb1.w;
        op[2] = Tb2.x * vx + Tb2.y * vy + Tb2.z * vz + Tb2.w;
    }
}

extern "C" void kernel_launch(void* const* d_in, const int* in_sizes, int n_in,
                              void* d_out, int out_size, void* d_ws, size_t ws_size,
                              hipStream_t stream) {
    const float* V    = (const float*)d_in[0];
    const float* J    = (const float*)d_in[1];
    const float* pose = (const float*)d_in[2];
    const float* W    = (const float*)d_in[3];
    float* out = (float*)d_out;
    float* Gc  = (float*)d_ws;  // NB*NJ*12 floats = 147456 B

    chain_kernel<<<NB, 64, 0, stream>>>(J, pose, Gc);
    dim3 grid((NV + 511) / 512, NB);
    lbs_kernel<<<grid, 256, 0, stream>>>(V, W, Gc, out);
}

// Round 5
// 26.949 us; speedup vs baseline: 1.5562x; 1.5562x over previous
//
#include <hip/hip_runtime.h>
#include <math.h>

#define NJ 24
#define NV 6890
#define NB 128

// Ancestor chains (closest ancestor first), -1 padded. Max depth 8.
__constant__ int d_anc[NJ][8] = {
  {-1,-1,-1,-1,-1,-1,-1,-1},
  { 0,-1,-1,-1,-1,-1,-1,-1},
  { 0,-1,-1,-1,-1,-1,-1,-1},
  { 0,-1,-1,-1,-1,-1,-1,-1},
  { 1, 0,-1,-1,-1,-1,-1,-1},
  { 2, 0,-1,-1,-1,-1,-1,-1},
  { 3, 0,-1,-1,-1,-1,-1,-1},
  { 4, 1, 0,-1,-1,-1,-1,-1},
  { 5, 2, 0,-1,-1,-1,-1,-1},
  { 6, 3, 0,-1,-1,-1,-1,-1},
  { 7, 4, 1, 0,-1,-1,-1,-1},
  { 8, 5, 2, 0,-1,-1,-1,-1},
  { 9, 6, 3, 0,-1,-1,-1,-1},
  { 9, 6, 3, 0,-1,-1,-1,-1},
  { 9, 6, 3, 0,-1,-1,-1,-1},
  {12, 9, 6, 3, 0,-1,-1,-1},
  {13, 9, 6, 3, 0,-1,-1,-1},
  {14, 9, 6, 3, 0,-1,-1,-1},
  {16,13, 9, 6, 3, 0,-1,-1},
  {17,14, 9, 6, 3, 0,-1,-1},
  {18,16,13, 9, 6, 3, 0,-1},
  {19,17,14, 9, 6, 3, 0,-1},
  {20,18,16,13, 9, 6, 3, 0},
  {21,19,17,14, 9, 6, 3, 0}
};
__constant__ int d_par[NJ] = {-1,0,0,0,1,2,3,4,5,6,7,8,9,9,9,12,13,14,16,17,18,19,20,21};

// Kernel 1: per-batch Rodrigues + parallel ancestor-path chain + J-correction.
__global__ __launch_bounds__(64) void chain_kernel(const float* __restrict__ J,
                                                   const float* __restrict__ pose,
                                                   float* __restrict__ Gc) {
    int b = blockIdx.x;
    int tid = threadIdx.x;
    __shared__ float A[NJ][12];   // local [R|t] per joint

    if (tid < NJ) {
        int i = tid;
        const float* p = pose + ((size_t)b * NJ + i) * 3;
        float rx = p[0], ry = p[1], rz = p[2];
        float ex = rx + 1e-8f, ey = ry + 1e-8f, ez = rz + 1e-8f;
        float theta = sqrtf(ex * ex + ey * ey + ez * ez);
        float inv = 1.0f / theta;
        float hx = rx * inv, hy = ry * inv, hz = rz * inv;
        float c = cosf(theta * (float)M_PI);
        float s = sinf(theta);
        float oc = 1.0f - c;
        const float* jp = J + ((size_t)b * NJ + i) * 3;
        int par = d_par[i];
        float tx, ty, tz;
        if (par < 0) {
            tx = jp[0]; ty = jp[1]; tz = jp[2];
        } else {
            const float* jq = J + ((size_t)b * NJ + par) * 3;
            tx = jp[0] - jq[0]; ty = jp[1] - jq[1]; tz = jp[2] - jq[2];
        }
        A[i][0]  = c + oc * hx * hx;
        A[i][1]  = oc * hx * hy - s * hz;
        A[i][2]  = oc * hx * hz + s * hy;
        A[i][3]  = tx;
        A[i][4]  = oc * hy * hx + s * hz;
        A[i][5]  = c + oc * hy * hy;
        A[i][6]  = oc * hy * hz - s * hx;
        A[i][7]  = ty;
        A[i][8]  = oc * hz * hx - s * hy;
        A[i][9]  = oc * hz * hy + s * hx;
        A[i][10] = c + oc * hz * hz;
        A[i][11] = tz;
    }
    __syncthreads();

    if (tid < NJ) {
        int i = tid;
        float M[12];
        #pragma unroll
        for (int j = 0; j < 12; j++) M[j] = A[i][j];

        for (int k = 0; k < 8; k++) {
            int p = d_anc[i][k];
            if (p < 0) break;
            float P[12];
            #pragma unroll
            for (int j = 0; j < 12; j++) P[j] = A[p][j];
            float N[12];
            #pragma unroll
            for (int r = 0; r < 3; r++) {
                float p0 = P[r*4+0], p1 = P[r*4+1], p2 = P[r*4+2], p3 = P[r*4+3];
                N[r*4+0] = p0 * M[0] + p1 * M[4] + p2 * M[8];
                N[r*4+1] = p0 * M[1] + p1 * M[5] + p2 * M[9];
                N[r*4+2] = p0 * M[2] + p1 * M[6] + p2 * M[10];
                N[r*4+3] = p0 * M[3] + p1 * M[7] + p2 * M[11] + p3;
            }
            #pragma unroll
            for (int j = 0; j < 12; j++) M[j] = N[j];
        }

        const float* jp = J + ((size_t)b * NJ + i) * 3;
        float jx = jp[0], jy = jp[1], jz = jp[2];
        float* o = Gc + ((size_t)b * NJ + i) * 12;
        #pragma unroll
        for (int r = 0; r < 3; r++) {
            float g0 = M[r*4+0], g1 = M[r*4+1], g2 = M[r*4+2], g3 = M[r*4+3];
            float corr = g0 * jx + g1 * jy + g2 * jz;
            o[r*4+0] = g0;
            o[r*4+1] = g1;
            o[r*4+2] = g2;
            o[r*4+3] = g3 - corr;
        }
    }
}

typedef __attribute__((ext_vector_type(16))) float fx16;

// Kernel 2: per-vertex skinning, 1 vertex/thread.
// Gc[b] (wave-uniform, 1152 B) is pulled through the SCALAR path:
// 3x s_load_dwordx16 per 4-joint chunk -> 48 SGPRs, consumed as the
// scalar operand of v_fmac_f32. No LDS, 18 SMEM instr/wave instead of
// 288 per-lane VMEM (R3) or 72 ds_read_b128 (R4).
__global__ __launch_bounds__(256) void lbs_kernel(const float* __restrict__ V,
                                                  const float* __restrict__ W,
                                                  const float* __restrict__ Gc,
                                                  float* __restrict__ out) {
    const int b = blockIdx.y;
    const int n = blockIdx.x * 256 + threadIdx.x;
    if (n >= NV) return;

    const float* gb = Gc + (size_t)b * (NJ * 12);

    const float4* wp = (const float4*)(W + ((size_t)b * NV + n) * 24);
    float4 warr[6];
    #pragma unroll
    for (int k = 0; k < 6; k++) warr[k] = wp[k];

    float T[12];
    #pragma unroll
    for (int j = 0; j < 12; j++) T[j] = 0.0f;

    #pragma unroll
    for (int c = 0; c < 6; c++) {
        // 4 joints (48 floats) of Gc[b] into SGPRs.
        fx16 ga, gB, gC;
        const float* p = gb + c * 48;
        asm volatile("s_load_dwordx16 %0, %3, 0x0\n\t"
                     "s_load_dwordx16 %1, %3, 0x40\n\t"
                     "s_load_dwordx16 %2, %3, 0x80\n\t"
                     "s_waitcnt lgkmcnt(0)"
                     : "=&s"(ga), "=&s"(gB), "=&s"(gC)
                     : "s"(p));

        const float wm[4] = {warr[c].x, warr[c].y, warr[c].z, warr[c].w};
        #pragma unroll
        for (int q = 0; q < 4; q++) {
            float wq = wm[q];
            #pragma unroll
            for (int j = 0; j < 12; j++) {
                const int flat = q * 12 + j;
                float g = (flat < 16) ? ga[flat < 16 ? flat : 0]
                        : (flat < 32) ? gB[flat >= 16 && flat < 32 ? flat - 16 : 0]
                                      : gC[flat >= 32 ? flat - 32 : 0];
                T[j] = fmaf(wq, g, T[j]);
            }
        }
    }

    const float* vp = V + ((size_t)b * NV + n) * 3;
    float vx = vp[0], vy = vp[1], vz = vp[2];
    float* op = out + ((size_t)b * NV + n) * 3;
    op[0] = T[0] * vx + T[1] * vy + T[2]  * vz + T[3];
    op[1] = T[4] * vx + T[5] * vy + T[6]  * vz + T[7];
    op[2] = T[8] * vx + T[9] * vy + T[10] * vz + T[11];
}

extern "C" void kernel_launch(void* const* d_in, const int* in_sizes, int n_in,
                              void* d_out, int out_size, void* d_ws, size_t ws_size,
                              hipStream_t stream) {
    const float* V    = (const float*)d_in[0];
    const float* J    = (const float*)d_in[1];
    const float* pose = (const float*)d_in[2];
    const float* W    = (const float*)d_in[3];
    float* out = (float*)d_out;
    float* Gc  = (float*)d_ws;  // NB*NJ*12 floats = 147456 B

    chain_kernel<<<NB, 64, 0, stream>>>(J, pose, Gc);
    dim3 grid((NV + 255) / 256, NB);
    lbs_kernel<<<grid, 256, 0, stream>>>(V, W, Gc, out);
}

// Round 6
// 26.556 us; speedup vs baseline: 1.5792x; 1.0148x over previous
//
#include <hip/hip_runtime.h>
#include <math.h>

#define NJ 24
#define NV 6890
#define NB 128

// Ancestor chains (closest ancestor first), -1 padded. Max depth 8.
__constant__ int d_anc[NJ][8] = {
  {-1,-1,-1,-1,-1,-1,-1,-1},
  { 0,-1,-1,-1,-1,-1,-1,-1},
  { 0,-1,-1,-1,-1,-1,-1,-1},
  { 0,-1,-1,-1,-1,-1,-1,-1},
  { 1, 0,-1,-1,-1,-1,-1,-1},
  { 2, 0,-1,-1,-1,-1,-1,-1},
  { 3, 0,-1,-1,-1,-1,-1,-1},
  { 4, 1, 0,-1,-1,-1,-1,-1},
  { 5, 2, 0,-1,-1,-1,-1,-1},
  { 6, 3, 0,-1,-1,-1,-1,-1},
  { 7, 4, 1, 0,-1,-1,-1,-1},
  { 8, 5, 2, 0,-1,-1,-1,-1},
  { 9, 6, 3, 0,-1,-1,-1,-1},
  { 9, 6, 3, 0,-1,-1,-1,-1},
  { 9, 6, 3, 0,-1,-1,-1,-1},
  {12, 9, 6, 3, 0,-1,-1,-1},
  {13, 9, 6, 3, 0,-1,-1,-1},
  {14, 9, 6, 3, 0,-1,-1,-1},
  {16,13, 9, 6, 3, 0,-1,-1},
  {17,14, 9, 6, 3, 0,-1,-1},
  {18,16,13, 9, 6, 3, 0,-1},
  {19,17,14, 9, 6, 3, 0,-1},
  {20,18,16,13, 9, 6, 3, 0},
  {21,19,17,14, 9, 6, 3, 0}
};
__constant__ int d_par[NJ] = {-1,0,0,0,1,2,3,4,5,6,7,8,9,9,9,12,13,14,16,17,18,19,20,21};

// Kernel 1: per-batch Rodrigues + parallel ancestor-path chain + J-correction.
// Output layout TRANSPOSED for the pk_fma path: Gc_t[b][j][m], j=r*4+c (12),
// m contiguous (24). So {Gc_t[j][m], Gc_t[j][m+1]} is an aligned SGPR pair.
__global__ __launch_bounds__(64) void chain_kernel(const float* __restrict__ J,
                                                   const float* __restrict__ pose,
                                                   float* __restrict__ Gc) {
    int b = blockIdx.x;
    int tid = threadIdx.x;
    __shared__ float A[NJ][12];   // local [R|t] per joint

    if (tid < NJ) {
        int i = tid;
        const float* p = pose + ((size_t)b * NJ + i) * 3;
        float rx = p[0], ry = p[1], rz = p[2];
        float ex = rx + 1e-8f, ey = ry + 1e-8f, ez = rz + 1e-8f;
        float theta = sqrtf(ex * ex + ey * ey + ez * ez);
        float inv = 1.0f / theta;
        float hx = rx * inv, hy = ry * inv, hz = rz * inv;
        float c = cosf(theta * (float)M_PI);
        float s = sinf(theta);
        float oc = 1.0f - c;
        const float* jp = J + ((size_t)b * NJ + i) * 3;
        int par = d_par[i];
        float tx, ty, tz;
        if (par < 0) {
            tx = jp[0]; ty = jp[1]; tz = jp[2];
        } else {
            const float* jq = J + ((size_t)b * NJ + par) * 3;
            tx = jp[0] - jq[0]; ty = jp[1] - jq[1]; tz = jp[2] - jq[2];
        }
        A[i][0]  = c + oc * hx * hx;
        A[i][1]  = oc * hx * hy - s * hz;
        A[i][2]  = oc * hx * hz + s * hy;
        A[i][3]  = tx;
        A[i][4]  = oc * hy * hx + s * hz;
        A[i][5]  = c + oc * hy * hy;
        A[i][6]  = oc * hy * hz - s * hx;
        A[i][7]  = ty;
        A[i][8]  = oc * hz * hx - s * hy;
        A[i][9]  = oc * hz * hy + s * hx;
        A[i][10] = c + oc * hz * hz;
        A[i][11] = tz;
    }
    __syncthreads();

    if (tid < NJ) {
        int i = tid;
        float M[12];
        #pragma unroll
        for (int j = 0; j < 12; j++) M[j] = A[i][j];

        for (int k = 0; k < 8; k++) {
            int p = d_anc[i][k];
            if (p < 0) break;
            float P[12];
            #pragma unroll
            for (int j = 0; j < 12; j++) P[j] = A[p][j];
            float N[12];
            #pragma unroll
            for (int r = 0; r < 3; r++) {
                float p0 = P[r*4+0], p1 = P[r*4+1], p2 = P[r*4+2], p3 = P[r*4+3];
                N[r*4+0] = p0 * M[0] + p1 * M[4] + p2 * M[8];
                N[r*4+1] = p0 * M[1] + p1 * M[5] + p2 * M[9];
                N[r*4+2] = p0 * M[2] + p1 * M[6] + p2 * M[10];
                N[r*4+3] = p0 * M[3] + p1 * M[7] + p2 * M[11] + p3;
            }
            #pragma unroll
            for (int j = 0; j < 12; j++) M[j] = N[j];
        }

        const float* jp = J + ((size_t)b * NJ + i) * 3;
        float jx = jp[0], jy = jp[1], jz = jp[2];
        float* o = Gc + (size_t)b * 288;   // [12][24]
        #pragma unroll
        for (int r = 0; r < 3; r++) {
            float g0 = M[r*4+0], g1 = M[r*4+1], g2 = M[r*4+2], g3 = M[r*4+3];
            float corr = g0 * jx + g1 * jy + g2 * jz;
            o[(r*4+0)*24 + i] = g0;
            o[(r*4+1)*24 + i] = g1;
            o[(r*4+2)*24 + i] = g2;
            o[(r*4+3)*24 + i] = g3 - corr;
        }
    }
}

typedef __attribute__((ext_vector_type(16))) float fx16;
typedef __attribute__((ext_vector_type(2)))  float f2;

__device__ __forceinline__ f2 mkf2(float a, float b) { f2 r; r.x = a; r.y = b; return r; }

// e is a compile-time constant after unrolling; &15 keeps dead arms in range.
#define GPAIR(e) ((e) < 16 ? mkf2(gA[(e) & 15], gA[((e) + 1) & 15]) \
                : (e) < 32 ? mkf2(gB[((e) - 16) & 15], gB[((e) - 15) & 15]) \
                           : mkf2(gC[((e) - 32) & 15], gC[((e) - 31) & 15]))

// Kernel 2: per-vertex skinning, 1 vertex/thread.
// Gc_t[b] pulled through the scalar path (18x s_load_dwordx16 per wave),
// blend via v_pk_fma_f32: pack over joint pairs (m, m+1). W pairs are the
// natural low/high halves of the float4 loads (zero packing cost); Gc pairs
// are adjacent SGPRs in the transposed layout. 144 pk-fma vs 288 scalar.
__global__ __launch_bounds__(256) void lbs_kernel(const float* __restrict__ V,
                                                  const float* __restrict__ W,
                                                  const float* __restrict__ Gc,
                                                  float* __restrict__ out) {
    const int b = blockIdx.y;
    const int n = blockIdx.x * 256 + threadIdx.x;
    if (n >= NV) return;

    const float* gb = Gc + (size_t)b * 288;

    const float4* wp = (const float4*)(W + ((size_t)b * NV + n) * 24);
    float4 w4[6];
    #pragma unroll
    for (int k = 0; k < 6; k++) w4[k] = wp[k];
    // Joint-pair view of W: wpr[q] = {w[2q], w[2q+1]}
    f2 wpr[12];
    #pragma unroll
    for (int k = 0; k < 6; k++) {
        wpr[2 * k + 0] = mkf2(w4[k].x, w4[k].y);
        wpr[2 * k + 1] = mkf2(w4[k].z, w4[k].w);
    }

    f2 T2[12];
    #pragma unroll
    for (int j = 0; j < 12; j++) T2[j] = mkf2(0.0f, 0.0f);

    #pragma unroll
    for (int c = 0; c < 6; c++) {
        // rows j=2c (offsets 0..23) and j=2c+1 (offsets 24..47) of Gc_t[b]
        fx16 gA, gB, gC;
        const float* p = gb + c * 48;
        asm volatile("s_load_dwordx16 %0, %3, 0x0\n\t"
                     "s_load_dwordx16 %1, %3, 0x40\n\t"
                     "s_load_dwordx16 %2, %3, 0x80\n\t"
                     "s_waitcnt lgkmcnt(0)"
                     : "=&s"(gA), "=&s"(gB), "=&s"(gC)
                     : "s"(p));

        f2 TA = T2[2 * c + 0];
        f2 TB = T2[2 * c + 1];
        #pragma unroll
        for (int q = 0; q < 12; q++) {
            f2 gpA = GPAIR(2 * q);
            f2 gpB = GPAIR(24 + 2 * q);
            asm("v_pk_fma_f32 %0, %1, %2, %0" : "+v"(TA) : "v"(wpr[q]), "s"(gpA));
            asm("v_pk_fma_f32 %0, %1, %2, %0" : "+v"(TB) : "v"(wpr[q]), "s"(gpB));
        }
        T2[2 * c + 0] = TA;
        T2[2 * c + 1] = TB;
    }

    float T[12];
    #pragma unroll
    for (int j = 0; j < 12; j++) T[j] = T2[j].x + T2[j].y;

    const float* vp = V + ((size_t)b * NV + n) * 3;
    float vx = vp[0], vy = vp[1], vz = vp[2];
    float* op = out + ((size_t)b * NV + n) * 3;
    op[0] = T[0] * vx + T[1] * vy + T[2]  * vz + T[3];
    op[1] = T[4] * vx + T[5] * vy + T[6]  * vz + T[7];
    op[2] = T[8] * vx + T[9] * vy + T[10] * vz + T[11];
}

extern "C" void kernel_launch(void* const* d_in, const int* in_sizes, int n_in,
                              void* d_out, int out_size, void* d_ws, size_t ws_size,
                              hipStream_t stream) {
    const float* V    = (const float*)d_in[0];
    const float* J    = (const float*)d_in[1];
    const float* pose = (const float*)d_in[2];
    const float* W    = (const float*)d_in[3];
    float* out = (float*)d_out;
    float* Gc  = (float*)d_ws;  // NB*288 floats = 147456 B

    chain_kernel<<<NB, 64, 0, stream>>>(J, pose, Gc);
    dim3 grid((NV + 255) / 256, NB);
    lbs_kernel<<<grid, 256, 0, stream>>>(V, W, Gc, out);
}